// Round 3
// baseline (1412.796 us; speedup 1.0000x reference)
//
#include <hip/hip_runtime.h>
#include <cstdint>
#include <cstddef>

// GateAttentionLayer: B=8, L=2048, D=1024, QK=128, UV=2048.
// I/O is FLOAT32 (per reference setup_inputs); internal compute bf16 MFMA
// (tolerance is 2% of max|ref|). Intermediates in ws are bf16.
//   qk = gelu(queries@Wqk + bqk); q = rope(qk*gq+betq); k = rope(qk*gk+betk)
//   vT = gelu(Wv^T @ values^T + bv)         (computed transposed for attn@v)
//   ug = gelu(u@Wu + bu)
//   attn = softmax(q@k^T / sqrt(QK))        (output #2, fp32)
//   out  = ug * (attn @ v);  o = out@Wo + bo (output #1, fp32)

#define B_  8
#define L_  2048
#define D_  1024
#define QK_ 128
#define UV_ 2048

typedef __bf16 bf16x8 __attribute__((ext_vector_type(8)));
typedef float  f32x4  __attribute__((ext_vector_type(4)));

__device__ __forceinline__ float b2f(unsigned short u) {
  return __uint_as_float(((unsigned int)u) << 16);
}
__device__ __forceinline__ unsigned short f2b(float f) {
  unsigned int u = __float_as_uint(f);
  u += 0x7fffu + ((u >> 16) & 1u);          // round-to-nearest-even
  return (unsigned short)(u >> 16);
}
__device__ __forceinline__ unsigned int pk2(float a, float b) {
  return (unsigned int)f2b(a) | ((unsigned int)f2b(b) << 16);
}
__device__ __forceinline__ float gelu_t(float x) {  // jax.nn.gelu approximate=True
  float x3 = x * x * x;
  return 0.5f * x * (1.0f + tanhf(0.7978845608028654f * (x + 0.044715f * x3)));
}

// ---------------- shared GEMM core: C_tile += A(M,K) @ Bt(N,K)^T ----------------
// block = 256 threads (4 waves, 2x2 wave grid, each wave 64x64 = 4x4 MFMA tiles)
// LDS: As/Bs row-major 128x32 bf16 (8KB each). AF32/BF32: that operand is fp32
// in global memory and is converted to bf16 during staging.
template <bool AF32, bool BF32>
__device__ __forceinline__ void gemm_core(
    const void* __restrict__ Ap, int lda,
    const void* __restrict__ Bp, int ldb,
    int K, int tileM, int tileN,
    unsigned short* As, unsigned short* Bs,
    f32x4 acc[4][4])
{
  const int tid  = threadIdx.x;
  const int wave = tid >> 6, lane = tid & 63;
  const int lr = lane & 15, lq = lane >> 4;
  const int wr = wave >> 1, wc = wave & 1;

  const int rb = tid >> 2, cb = (tid & 3) << 3;   // bf16 staging: 2 rows x 8 elems
  const int rf = tid >> 1, cf = (tid & 1) << 4;   // f32  staging: 1 row x 16 elems

  for (int k0 = 0; k0 < K; k0 += 32) {
    float4 fa0, fa1, fa2, fa3, fb0, fb1, fb2, fb3;
    uint4 ua0, ua1, ub0, ub1;
    if constexpr (AF32) {
      const float* g = (const float*)Ap + (size_t)(tileM + rf) * lda + cf + k0;
      fa0 = ((const float4*)g)[0]; fa1 = ((const float4*)g)[1];
      fa2 = ((const float4*)g)[2]; fa3 = ((const float4*)g)[3];
    } else {
      const unsigned short* g = (const unsigned short*)Ap + (size_t)(tileM + rb) * lda + cb + k0;
      ua0 = *(const uint4*)g;
      ua1 = *(const uint4*)(g + (size_t)64 * lda);
    }
    if constexpr (BF32) {
      const float* g = (const float*)Bp + (size_t)(tileN + rf) * ldb + cf + k0;
      fb0 = ((const float4*)g)[0]; fb1 = ((const float4*)g)[1];
      fb2 = ((const float4*)g)[2]; fb3 = ((const float4*)g)[3];
    } else {
      const unsigned short* g = (const unsigned short*)Bp + (size_t)(tileN + rb) * ldb + cb + k0;
      ub0 = *(const uint4*)g;
      ub1 = *(const uint4*)(g + (size_t)64 * ldb);
    }
    __syncthreads();                        // previous iteration's frag reads done
    if constexpr (AF32) {
      *(uint4*)(As + rf * 32 + cf)     = make_uint4(pk2(fa0.x, fa0.y), pk2(fa0.z, fa0.w), pk2(fa1.x, fa1.y), pk2(fa1.z, fa1.w));
      *(uint4*)(As + rf * 32 + cf + 8) = make_uint4(pk2(fa2.x, fa2.y), pk2(fa2.z, fa2.w), pk2(fa3.x, fa3.y), pk2(fa3.z, fa3.w));
    } else {
      *(uint4*)(As + rb * 32 + cb)        = ua0;
      *(uint4*)(As + (rb + 64) * 32 + cb) = ua1;
    }
    if constexpr (BF32) {
      *(uint4*)(Bs + rf * 32 + cf)     = make_uint4(pk2(fb0.x, fb0.y), pk2(fb0.z, fb0.w), pk2(fb1.x, fb1.y), pk2(fb1.z, fb1.w));
      *(uint4*)(Bs + rf * 32 + cf + 8) = make_uint4(pk2(fb2.x, fb2.y), pk2(fb2.z, fb2.w), pk2(fb3.x, fb3.y), pk2(fb3.z, fb3.w));
    } else {
      *(uint4*)(Bs + rb * 32 + cb)        = ub0;
      *(uint4*)(Bs + (rb + 64) * 32 + cb) = ub1;
    }
    __syncthreads();                        // staging visible
    bf16x8 af[4], bfr[4];
#pragma unroll
    for (int i = 0; i < 4; ++i)
      af[i] = *(const bf16x8*)(As + ((wr * 64 + i * 16 + lr) << 5) + (lq << 3));
#pragma unroll
    for (int i = 0; i < 4; ++i)
      bfr[i] = *(const bf16x8*)(Bs + ((wc * 64 + i * 16 + lr) << 5) + (lq << 3));
#pragma unroll
    for (int mi = 0; mi < 4; ++mi)
#pragma unroll
      for (int ni = 0; ni < 4; ++ni)
        acc[mi][ni] = __builtin_amdgcn_mfma_f32_16x16x32_bf16(af[mi], bfr[ni], acc[mi][ni], 0, 0, 0);
  }
}

// EPI: 0 = gelu(x+bias[col]); 1 = gelu(x+bias[row]); 2 = x+bias[col];
//      3 = x*scale; 4 = x*gate[row,col]   (bias fp32, gate bf16)
// CF32: C is fp32; else bf16.
template <int EPI, bool AF32, bool BF32, bool CF32>
__global__ void __launch_bounds__(256) gemm_bt_epi(
    const void* __restrict__ A, int lda, long long sA,
    const void* __restrict__ Bt, int ldb, long long sB,
    void* C, int ldc, long long sC,
    int K,
    const float* __restrict__ bias,
    const unsigned short* gate, long long sG,
    float scale)
{
  __shared__ __align__(16) unsigned short As[128 * 32];
  __shared__ __align__(16) unsigned short Bs[128 * 32];
  const int z = blockIdx.z;
  const void* Az = AF32 ? (const void*)((const float*)A + (size_t)z * sA)
                        : (const void*)((const unsigned short*)A + (size_t)z * sA);
  const void* Bz = BF32 ? (const void*)((const float*)Bt + (size_t)z * sB)
                        : (const void*)((const unsigned short*)Bt + (size_t)z * sB);
  float* Cf = CF32 ? (float*)C + (size_t)z * sC : nullptr;
  unsigned short* Cb = CF32 ? nullptr : (unsigned short*)C + (size_t)z * sC;
  const unsigned short* gateb = gate ? gate + (size_t)z * sG : nullptr;
  const int tileM = blockIdx.y * 128, tileN = blockIdx.x * 128;

  f32x4 acc[4][4] = {};
  gemm_core<AF32, BF32>(Az, lda, Bz, ldb, K, tileM, tileN, As, Bs, acc);

  const int lane = threadIdx.x & 63, wave = threadIdx.x >> 6;
  const int lr = lane & 15, lq = lane >> 4;
  const int wr = wave >> 1, wc = wave & 1;
#pragma unroll
  for (int mi = 0; mi < 4; ++mi) {
#pragma unroll
    for (int r = 0; r < 4; ++r) {
      const int row = tileM + wr * 64 + mi * 16 + lq * 4 + r;   // C: row=(lane>>4)*4+reg
#pragma unroll
      for (int ni = 0; ni < 4; ++ni) {
        const int col = tileN + wc * 64 + ni * 16 + lr;         // C: col=lane&15
        float x = acc[mi][ni][r];
        if constexpr (EPI == 0)      x = gelu_t(x + bias[col]);
        else if constexpr (EPI == 1) x = gelu_t(x + bias[row]);
        else if constexpr (EPI == 2) x = x + bias[col];
        else if constexpr (EPI == 3) x = x * scale;
        else if constexpr (EPI == 4) x = x * b2f(gateb[(size_t)row * ldc + col]);
        if constexpr (CF32) Cf[(size_t)row * ldc + col] = x;
        else                Cb[(size_t)row * ldc + col] = f2b(x);
      }
    }
  }
}

// qk GEMM with fused bias+gelu, scale/shift, and RoPE epilogue. N=QK=128 (one tile).
// A = queries (fp32), Bt = WqkT (bf16); outputs q,k bf16.
__global__ void __launch_bounds__(256) qk_rope(
    const float* __restrict__ A,
    const unsigned short* __restrict__ Bt,
    unsigned short* __restrict__ qo, unsigned short* __restrict__ ko,
    const float* __restrict__ bqk,
    const float* __restrict__ gq, const float* __restrict__ betq,
    const float* __restrict__ gk, const float* __restrict__ betk)
{
  __shared__ __align__(16) unsigned short As[128 * 32];
  __shared__ __align__(16) unsigned short Bs[128 * 32];
  const int tileM = blockIdx.y * 128;
  f32x4 acc[4][4] = {};
  gemm_core<true, false>(A, D_, Bt, D_, D_, tileM, 0, As, Bs, acc);

  const int lane = threadIdx.x & 63, wave = threadIdx.x >> 6;
  const int lr = lane & 15, lq = lane >> 4;
  const int wr = wave >> 1, wc = wave & 1;
#pragma unroll
  for (int mi = 0; mi < 4; ++mi) {
#pragma unroll
    for (int r = 0; r < 4; ++r) {
      const int row = tileM + wr * 64 + mi * 16 + lq * 4 + r;
      const int l   = row & (L_ - 1);       // position within batch
#pragma unroll
      for (int ni = 0; ni < 4; ++ni) {
        const int n = wc * 64 + ni * 16 + lr;   // col in [0,128)
        float x  = gelu_t(acc[mi][ni][r] + bqk[n]);
        float qv = x * gq[n] + betq[n];
        float kv = x * gk[n] + betk[n];
        const int p = n >> 1;
        // inv_freq = 10000^(-p/64) = exp(-p * ln(10000)/64)
        float ang = (float)l * expf(-0.14391156831212787f * (float)p);
        float c = cosf(ang), s = sinf(ang);
        // RoPE pair (2i,2i+1) = adjacent lanes (col parity == lane parity)
        float qvo = __shfl_xor(qv, 1);
        float kvo = __shfl_xor(kv, 1);
        float qr = (n & 1) ? (qvo * s + qv * c) : (qv * c - qvo * s);
        float kr = (n & 1) ? (kvo * s + kv * c) : (kv * c - kvo * s);
        qo[(size_t)row * QK_ + n] = f2b(qr);
        ko[(size_t)row * QK_ + n] = f2b(kr);
      }
    }
  }
}

// in-place row softmax over n=2048 fp32 elements, one block (256 thr) per row
__global__ void __launch_bounds__(256) softmax_rows(float* attn, int n)
{
  const int row = blockIdx.x;
  float4* rp = (float4*)(attn + (size_t)row * n);
  const int tid = threadIdx.x, lane = tid & 63, wave = tid >> 6;
  float4 d0 = rp[tid], d1 = rp[tid + 256];
  float v[8] = { d0.x, d0.y, d0.z, d0.w, d1.x, d1.y, d1.z, d1.w };
  float m = v[0];
#pragma unroll
  for (int i = 1; i < 8; ++i) m = fmaxf(m, v[i]);
  for (int off = 32; off > 0; off >>= 1) m = fmaxf(m, __shfl_xor(m, off));
  __shared__ float redm[4], reds[4];
  if (lane == 0) redm[wave] = m;
  __syncthreads();
  m = fmaxf(fmaxf(redm[0], redm[1]), fmaxf(redm[2], redm[3]));
  float s = 0.f;
#pragma unroll
  for (int i = 0; i < 8; ++i) { v[i] = __expf(v[i] - m); s += v[i]; }
  for (int off = 32; off > 0; off >>= 1) s += __shfl_xor(s, off);
  if (lane == 0) reds[wave] = s;
  __syncthreads();
  s = reds[0] + reds[1] + reds[2] + reds[3];
  const float inv = 1.0f / s;
  rp[tid]       = make_float4(v[0] * inv, v[1] * inv, v[2] * inv, v[3] * inv);
  rp[tid + 256] = make_float4(v[4] * inv, v[5] * inv, v[6] * inv, v[7] * inv);
}

// (R,C) fp32 -> (C,R) bf16 transpose, 32x32 LDS tiles, block (32,8)
__global__ void transpose_k(const float* __restrict__ in, unsigned short* __restrict__ out,
                            int R, int C)
{
  __shared__ float t[32][33];
  const int c0 = blockIdx.x * 32, r0 = blockIdx.y * 32;
  const int tx = threadIdx.x, ty = threadIdx.y;
  for (int j = ty; j < 32; j += 8) t[j][tx] = in[(size_t)(r0 + j) * C + c0 + tx];
  __syncthreads();
  for (int j = ty; j < 32; j += 8) out[(size_t)(c0 + j) * R + r0 + tx] = f2b(t[tx][j]);
}

extern "C" void kernel_launch(void* const* d_in, const int* in_sizes, int n_in,
                              void* d_out, int out_size, void* d_ws, size_t ws_size,
                              hipStream_t stream)
{
  const float* u_p  = (const float*)d_in[0];
  const float* qry  = (const float*)d_in[1];
  // d_in[2] = keys : unused by the reference
  const float* vals = (const float*)d_in[3];
  const float* Wqk  = (const float*)d_in[4];
  const float* bqk  = (const float*)d_in[5];
  const float* gq   = (const float*)d_in[6];
  const float* betq = (const float*)d_in[7];
  const float* gk   = (const float*)d_in[8];
  const float* betk = (const float*)d_in[9];
  const float* Wv   = (const float*)d_in[10];
  const float* bv   = (const float*)d_in[11];
  const float* Wu   = (const float*)d_in[12];
  const float* bu   = (const float*)d_in[13];
  const float* Wo   = (const float*)d_in[14];
  const float* bo   = (const float*)d_in[15];

  float* o_out = (float*)d_out;                                   // (B*L, D) fp32
  float* attn  = o_out + (size_t)B_ * L_ * D_;                    // (B, L, L) fp32

  unsigned short* ws   = (unsigned short*)d_ws;                   // bf16 intermediates
  unsigned short* WqkT = ws;                                      // (QK, D)
  unsigned short* WvT  = WqkT + (size_t)QK_ * D_;                 // (UV, D)
  unsigned short* WuT  = WvT  + (size_t)UV_ * D_;                 // (UV, D)
  unsigned short* WoT  = WuT  + (size_t)UV_ * D_;                 // (D, UV)
  unsigned short* qb   = WoT  + (size_t)D_ * UV_;                 // (B*L, QK)
  unsigned short* kb   = qb   + (size_t)B_ * L_ * QK_;            // (B*L, QK)
  unsigned short* vT   = kb   + (size_t)B_ * L_ * QK_;            // (B, UV, L)
  unsigned short* ug   = vT   + (size_t)B_ * UV_ * L_;            // (B*L, UV); reused as `out`

  const dim3 tb(32, 8);
  transpose_k<<<dim3(QK_ / 32, D_ / 32, 1), tb, 0, stream>>>(Wqk, WqkT, D_, QK_);
  transpose_k<<<dim3(UV_ / 32, D_ / 32, 1), tb, 0, stream>>>(Wv, WvT, D_, UV_);
  transpose_k<<<dim3(UV_ / 32, D_ / 32, 1), tb, 0, stream>>>(Wu, WuT, D_, UV_);
  transpose_k<<<dim3(D_ / 32, UV_ / 32, 1), tb, 0, stream>>>(Wo, WoT, UV_, D_);

  // q,k (bias+gelu+scale/shift+rope fused)
  qk_rope<<<dim3(1, (B_ * L_) / 128, 1), 256, 0, stream>>>(qry, WqkT, qb, kb, bqk, gq, betq, gk, betk);

  // vT[b] = gelu(WvT @ values[b]^T + bv[row]) : M=UV, N=L, K=D (batched)
  gemm_bt_epi<1, false, true, false><<<dim3(L_ / 128, UV_ / 128, B_), 256, 0, stream>>>(
      WvT, D_, 0, vals, D_, (long long)L_ * D_, vT, L_, (long long)UV_ * L_, D_,
      bv, nullptr, 0, 0.f);

  // ug = gelu(u @ Wu + bu) : M=B*L, N=UV, K=D
  gemm_bt_epi<0, true, false, false><<<dim3(UV_ / 128, (B_ * L_) / 128, 1), 256, 0, stream>>>(
      u_p, D_, 0, WuT, D_, 0, ug, UV_, 0, D_, bu, nullptr, 0, 0.f);

  // scores = q @ k^T / sqrt(QK) : per batch M=N=L, K=QK ; fp32 out
  gemm_bt_epi<3, false, false, true><<<dim3(L_ / 128, L_ / 128, B_), 256, 0, stream>>>(
      qb, QK_, (long long)L_ * QK_, kb, QK_, (long long)L_ * QK_,
      attn, L_, (long long)L_ * L_, QK_, nullptr, nullptr, 0, 0.08838834764831845f);

  softmax_rows<<<dim3(B_ * L_), 256, 0, stream>>>(attn, L_);

  // out = ug * (attn @ v) : per batch M=L, N=UV, K=L ; A fp32, in place over ug
  gemm_bt_epi<4, true, false, false><<<dim3(UV_ / 128, L_ / 128, B_), 256, 0, stream>>>(
      attn, L_, (long long)L_ * L_, vT, L_, (long long)UV_ * L_,
      ug, UV_, (long long)L_ * UV_, L_, nullptr, ug, (long long)L_ * UV_, 0.f);

  // o = out @ Wo + bo : M=B*L, N=D, K=UV ; fp32 out
  gemm_bt_epi<2, false, false, true><<<dim3(D_ / 128, (B_ * L_) / 128, 1), 256, 0, stream>>>(
      ug, UV_, 0, WoT, UV_, 0, o_out, D_, 0, UV_, bo, nullptr, 0, 0.f);
}